// Round 6
// baseline (431.353 us; speedup 1.0000x reference)
//
#include <hip/hip_runtime.h>

#define T_ 1024
#define H_ 2048
#define I_ 3200
#define E_ 8

typedef float fvec4 __attribute__((ext_vector_type(4)));
typedef float f32x4 __attribute__((ext_vector_type(4)));
typedef __bf16 bf16x8 __attribute__((ext_vector_type(8)));
typedef unsigned short u16x4 __attribute__((ext_vector_type(4)));

typedef const __attribute__((address_space(1))) void* gp1_t;
typedef __attribute__((address_space(3))) void* sp3_t;

// ---- ws layout (bytes) ----
// 0    : cnt[8]
// 64   : base[16]
// 128  : nchunks, chunkE[24], chunkM[24]
// 512  : tok_list[8*1024] int
// 33280: gate_list[8*1024] float
// 66560: xb [1024*2048] bf16 (4 MB)
// 4261888: actb [3328 x 3200] bf16 (21.3 MB, slack rows OOB-safe)
#define WS_CHUNK 128
#define WS_TOK   512
#define WS_GATE  33280
#define WS_XB    66560
#define WS_ACT   4261888
#define MAXCH    24

#define BARX() { asm volatile("s_waitcnt lgkmcnt(0)" ::: "memory"); \
    __builtin_amdgcn_sched_barrier(0); __builtin_amdgcn_s_barrier(); }

// ---------------- router + sparsemixer + list build + x->bf16 ----------------
__global__ __launch_bounds__(256) void router_kernel(const float* __restrict__ x,
                                                     const float* __restrict__ gw,
                                                     int* __restrict__ cnt,
                                                     int* __restrict__ tok,
                                                     float* __restrict__ gate,
                                                     unsigned short* __restrict__ xb) {
  const int lane = threadIdx.x & 63;
  const int wv = threadIdx.x >> 6;
  const int t = blockIdx.x * 4 + wv;

  const float* xp = x + (size_t)t * H_;
  fvec4 xr[8];
#pragma unroll
  for (int j = 0; j < 8; ++j) xr[j] = *(const fvec4*)(xp + j * 256 + lane * 4);

  unsigned short* xbp = xb + (size_t)t * H_;
#pragma unroll
  for (int j = 0; j < 8; ++j) {
    u16x4 o;
#pragma unroll
    for (int c = 0; c < 4; ++c) o[c] = __builtin_bit_cast(unsigned short, (__bf16)xr[j][c]);
    *(u16x4*)(xbp + j * 256 + lane * 4) = o;
  }

  float s[E_];
#pragma unroll
  for (int e = 0; e < E_; ++e) {
    const float* gp = gw + (size_t)e * H_;
    float p = 0.f;
#pragma unroll
    for (int j = 0; j < 8; ++j) {
      fvec4 g = *(const fvec4*)(gp + j * 256 + lane * 4);
      p = fmaf(xr[j][0], g[0], p); p = fmaf(xr[j][1], g[1], p);
      p = fmaf(xr[j][2], g[2], p); p = fmaf(xr[j][3], g[3], p);
    }
#pragma unroll
    for (int off = 32; off > 0; off >>= 1) p += __shfl_xor(p, off);
    s[e] = p;
  }

  float max1 = s[0]; int i1 = 0;
#pragma unroll
  for (int e = 1; e < E_; ++e) if (s[e] > max1) { max1 = s[e]; i1 = e; }
  float den1 = 0.f;
#pragma unroll
  for (int e = 0; e < E_; ++e) {
    float factor = fmaxf(fabsf(s[e]), max1);
    if ((max1 - s[e]) <= 0.02f * factor) den1 += expf(s[e] - max1);
  }
  float mult1 = 1.f / den1;

  float max2 = -INFINITY; int i2 = 0;
#pragma unroll
  for (int e = 0; e < E_; ++e) if (e != i1 && s[e] > max2) { max2 = s[e]; i2 = e; }
  float den2 = 0.f;
#pragma unroll
  for (int e = 0; e < E_; ++e) {
    if (e == i1) continue;
    float factor = fmaxf(fabsf(s[e]), max2);
    if ((max2 - s[e]) <= 0.02f * factor) den2 += expf(s[e] - max2);
  }
  float mult2 = 1.f / den2;

  if (lane == 0) {
    int p1 = atomicAdd(&cnt[i1], 1); tok[i1 * T_ + p1] = t; gate[i1 * T_ + p1] = mult1;
    int p2 = atomicAdd(&cnt[i2], 1); tok[i2 * T_ + p2] = t; gate[i2 * T_ + p2] = mult2;
  }
}

// ---------------- prefix + chunk table (256-row chunks) ----------------
__global__ void prefix_kernel(const int* __restrict__ cnt, int* __restrict__ base,
                              int* __restrict__ chunk) {
  if (threadIdx.x == 0 && blockIdx.x == 0) {
    int a = 0, c = 0;
    for (int e = 0; e < E_; ++e) {
      base[e] = a;
      int pc = (cnt[e] + 127) & ~127;
      for (int m = 0; m < pc; m += 256) { chunk[1 + c] = e; chunk[1 + MAXCH + c] = m; ++c; }
      a += pc;
    }
    base[E_] = a;
    chunk[0] = c;
  }
}

// ---------------- FFN1: BM=256, BN=64, BK=32, 8 waves, A 3-buf, 2 blocks/CU ----------------
__global__ __launch_bounds__(512, 4) void ffn1_kernel(
    const unsigned short* __restrict__ xb, const float* __restrict__ w1,
    const float* __restrict__ w3, const int* __restrict__ cnt,
    const int* __restrict__ base, const int* __restrict__ chunk,
    const int* __restrict__ tokl, unsigned short* __restrict__ actb) {
  if ((int)blockIdx.y >= chunk[0]) return;
  const int e = chunk[1 + blockIdx.y];
  const int m_base = chunk[1 + MAXCH + blockIdx.y];
  const int ab = base[e];
  const int count = cnt[e];
  const int n0 = blockIdx.x * 64;
  const int tid = threadIdx.x;
  const int lane = tid & 63, wv = tid >> 6;   // 8 waves
  const int wm = wv >> 1, wn = wv & 1;        // 4m x 2n; per-wave 64x32 out

  __shared__ unsigned short Abuf[3][256 * 32]; // 48 KiB
  __shared__ unsigned short B1s[2][64 * 32];   // 8 KiB
  __shared__ unsigned short B3s[2][64 * 32];   // 8 KiB  -> total 64 KiB

  // A stage sources: 2 glds/thread; row r covered: i*128 + wv*16 + (lane>>2)
  const unsigned short* aSrc[2];
#pragma unroll
  for (int i = 0; i < 2; ++i) {
    int r = i * 128 + wv * 16 + (lane >> 2);
    int rr = m_base + r;
    if (rr >= count) rr = count - 1;
    aSrc[i] = xb + (size_t)tokl[e * T_ + rr] * H_ + ((lane & 3) ^ (r & 3)) * 8;
  }
  // B: waves 0-3 load/convert w1, waves 4-7 w3 (uniform 2 loads/wave)
  const int bt = tid & 255;
  const int brow = bt >> 2, bg = bt & 3;
  const float* bp = ((wv < 4) ? w1 : w3) + ((size_t)e * I_ + n0 + brow) * H_ + bg * 8;
  const int wbyte = brow * 64 + ((bg ^ (brow & 3)) << 4);

  int aoff[4], rbof[2];
#pragma unroll
  for (int mi = 0; mi < 4; ++mi) {
    int ar = wm * 64 + mi * 16 + (lane & 15);
    aoff[mi] = ar * 64 + (((lane >> 4) ^ (ar & 3)) << 4);
  }
#pragma unroll
  for (int ni = 0; ni < 2; ++ni) {
    int br = wn * 32 + ni * 16 + (lane & 15);
    rbof[ni] = br * 64 + (((lane >> 4) ^ (br & 3)) << 4);
  }

  f32x4 acc1[4][2], acc3[4][2];
#pragma unroll
  for (int mi = 0; mi < 4; ++mi)
#pragma unroll
    for (int ni = 0; ni < 2; ++ni) { acc1[mi][ni] = (f32x4){0,0,0,0}; acc3[mi][ni] = (f32x4){0,0,0,0}; }

  auto STAGE = [&](unsigned short* dst, int kb) {
#pragma unroll
    for (int i = 0; i < 2; ++i)
      __builtin_amdgcn_global_load_lds((gp1_t)(aSrc[i] + kb),
          (sp3_t)(dst + (i * 128 + wv * 16) * 32), 16, 0, 0);
  };
  auto LOADB = [&](fvec4 (&r)[2], int kb) {
    r[0] = *(const fvec4*)(bp + kb);
    r[1] = *(const fvec4*)(bp + kb + 4);
  };
  auto CVTW = [&](fvec4 (&r)[2], int buf) {
    bf16x8 v;
#pragma unroll
    for (int c = 0; c < 4; ++c) { v[c] = (__bf16)r[0][c]; v[c + 4] = (__bf16)r[1][c]; }
    unsigned short* bb = (wv < 4) ? B1s[buf] : B3s[buf];
    *(bf16x8*)((char*)bb + wbyte) = v;
  };
  auto STEP = [&](const unsigned short* Ab, int bbuf) {
    bf16x8 af[4], f1[2], f3[2];
#pragma unroll
    for (int mi = 0; mi < 4; ++mi) af[mi] = *(const bf16x8*)((const char*)Ab + aoff[mi]);
#pragma unroll
    for (int ni = 0; ni < 2; ++ni) {
      f1[ni] = *(const bf16x8*)((const char*)B1s[bbuf] + rbof[ni]);
      f3[ni] = *(const bf16x8*)((const char*)B3s[bbuf] + rbof[ni]);
    }
    __builtin_amdgcn_s_setprio(1);
#pragma unroll
    for (int mi = 0; mi < 4; ++mi)
#pragma unroll
      for (int ni = 0; ni < 2; ++ni) {
        acc1[mi][ni] = __builtin_amdgcn_mfma_f32_16x16x32_bf16(af[mi], f1[ni], acc1[mi][ni], 0, 0, 0);
        acc3[mi][ni] = __builtin_amdgcn_mfma_f32_16x16x32_bf16(af[mi], f3[ni], acc3[mi][ni], 0, 0, 0);
      }
    __builtin_amdgcn_s_setprio(0);
  };

  const int NT = H_ / 32;  // 64 (even)
  unsigned short *A0 = Abuf[0], *A1 = Abuf[1], *A2 = Abuf[2];
  fvec4 rE[2], rO[2];

  STAGE(A0, 0);  LOADB(rE, 0);
  STAGE(A1, 32); LOADB(rO, 32);
  asm volatile("s_waitcnt vmcnt(4)" ::: "memory");
  CVTW(rE, 0);
  BARX();

  for (int t = 0; t < NT; t += 2) {
    // even region t: compute(A0, B0); stage t+2; convert B(t+1)
    if (t + 2 < NT) { STAGE(A2, (t + 2) * 32); LOADB(rE, (t + 2) * 32); }
    STEP(A0, 0);
    if (t + 2 < NT) { asm volatile("s_waitcnt vmcnt(4)" ::: "memory"); }
    else            { asm volatile("s_waitcnt vmcnt(0)" ::: "memory"); }
    CVTW(rO, 1);
    BARX();
    { unsigned short* tmp = A0; A0 = A1; A1 = A2; A2 = tmp; }
    // odd region t+1: compute(A0, B1); stage t+3; convert B(t+2)
    if (t + 3 < NT) { STAGE(A2, (t + 3) * 32); LOADB(rO, (t + 3) * 32); }
    STEP(A0, 1);
    if (t + 3 < NT) { asm volatile("s_waitcnt vmcnt(4)" ::: "memory"); }
    else            { asm volatile("s_waitcnt vmcnt(0)" ::: "memory"); }
    if (t + 2 < NT) CVTW(rE, 0);
    BARX();
    { unsigned short* tmp = A0; A0 = A1; A1 = A2; A2 = tmp; }
  }

  const int row_lim = (base[e + 1] - ab) - m_base;
#pragma unroll
  for (int mi = 0; mi < 4; ++mi)
#pragma unroll
    for (int ni = 0; ni < 2; ++ni)
#pragma unroll
      for (int j = 0; j < 4; ++j) {
        int row = wm * 64 + mi * 16 + (lane >> 4) * 4 + j;
        if (row < row_lim) {
          float h1 = acc1[mi][ni][j];
          float a = (h1 / (1.f + __expf(-h1))) * acc3[mi][ni][j];
          actb[(size_t)(ab + m_base + row) * I_ + n0 + wn * 32 + ni * 16 + (lane & 15)] =
              __builtin_bit_cast(unsigned short, (__bf16)a);
        }
      }
}

// ---------------- FFN2: BM=256, BN=64, BK=32, same pipeline, single B ----------------
__global__ __launch_bounds__(512, 4) void ffn2_kernel(
    const unsigned short* __restrict__ actb, const float* __restrict__ w2,
    const int* __restrict__ cnt, const int* __restrict__ base,
    const int* __restrict__ chunk, const int* __restrict__ tokl,
    const float* __restrict__ gatel, float* __restrict__ out) {
  if ((int)blockIdx.y >= chunk[0]) return;
  const int e = chunk[1 + blockIdx.y];
  const int m_base = chunk[1 + MAXCH + blockIdx.y];
  const int count = cnt[e];
  if (m_base >= count) return;
  const int ab = base[e];
  const int n0 = blockIdx.x * 64;
  const int tid = threadIdx.x;
  const int lane = tid & 63, wv = tid >> 6;
  const int wm = wv >> 1, wn = wv & 1;

  __shared__ unsigned short Abuf[3][256 * 32]; // 48 KiB
  __shared__ unsigned short Bs[2][64 * 32];    // 8 KiB  -> total 56 KiB

  const unsigned short* aSrc[2];
#pragma unroll
  for (int i = 0; i < 2; ++i) {
    int r = i * 128 + wv * 16 + (lane >> 2);
    aSrc[i] = actb + (size_t)(ab + m_base + r) * I_ + ((lane & 3) ^ (r & 3)) * 8;
  }
  const int brow = tid >> 3;                  // 64 rows, 8 thr/row
  const int bg = (tid & 7) >> 1, bh = tid & 1;
  const float* bp = w2 + ((size_t)e * H_ + n0 + brow) * I_ + (tid & 7) * 4;
  const int wbyte = brow * 64 + ((bg ^ (brow & 3)) << 4) + bh * 8;

  int aoff[4], rbof[2];
#pragma unroll
  for (int mi = 0; mi < 4; ++mi) {
    int ar = wm * 64 + mi * 16 + (lane & 15);
    aoff[mi] = ar * 64 + (((lane >> 4) ^ (ar & 3)) << 4);
  }
#pragma unroll
  for (int ni = 0; ni < 2; ++ni) {
    int br = wn * 32 + ni * 16 + (lane & 15);
    rbof[ni] = br * 64 + (((lane >> 4) ^ (br & 3)) << 4);
  }

  f32x4 acc[4][2];
#pragma unroll
  for (int mi = 0; mi < 4; ++mi)
#pragma unroll
    for (int ni = 0; ni < 2; ++ni) acc[mi][ni] = (f32x4){0,0,0,0};

  auto STAGE = [&](unsigned short* dst, int kb) {
#pragma unroll
    for (int i = 0; i < 2; ++i)
      __builtin_amdgcn_global_load_lds((gp1_t)(aSrc[i] + kb),
          (sp3_t)(dst + (i * 128 + wv * 16) * 32), 16, 0, 0);
  };
  auto LOADB = [&](fvec4& r, int kb) { r = *(const fvec4*)(bp + kb); };
  auto CVTW = [&](fvec4& r, int buf) {
    u16x4 v;
#pragma unroll
    for (int c = 0; c < 4; ++c) v[c] = __builtin_bit_cast(unsigned short, (__bf16)r[c]);
    *(u16x4*)((char*)Bs[buf] + wbyte) = v;
  };
  auto STEP = [&](const unsigned short* Ab, int bbuf) {
    bf16x8 af[4], f[2];
#pragma unroll
    for (int mi = 0; mi < 4; ++mi) af[mi] = *(const bf16x8*)((const char*)Ab + aoff[mi]);
#pragma unroll
    for (int ni = 0; ni < 2; ++ni) f[ni] = *(const bf16x8*)((const char*)Bs[bbuf] + rbof[ni]);
    __builtin_amdgcn_s_setprio(1);
#pragma unroll
    for (int mi = 0; mi < 4; ++mi)
#pragma unroll
      for (int ni = 0; ni < 2; ++ni)
        acc[mi][ni] = __builtin_amdgcn_mfma_f32_16x16x32_bf16(af[mi], f[ni], acc[mi][ni], 0, 0, 0);
    __builtin_amdgcn_s_setprio(0);
  };

  const int NT = I_ / 32;  // 100 (even)
  unsigned short *A0 = Abuf[0], *A1 = Abuf[1], *A2 = Abuf[2];
  fvec4 rEv, rOd;

  STAGE(A0, 0);  LOADB(rEv, 0);
  STAGE(A1, 32); LOADB(rOd, 32);
  asm volatile("s_waitcnt vmcnt(3)" ::: "memory");
  CVTW(rEv, 0);
  BARX();

  for (int t = 0; t < NT; t += 2) {
    if (t + 2 < NT) { STAGE(A2, (t + 2) * 32); LOADB(rEv, (t + 2) * 32); }
    STEP(A0, 0);
    if (t + 2 < NT) { asm volatile("s_waitcnt vmcnt(3)" ::: "memory"); }
    else            { asm volatile("s_waitcnt vmcnt(0)" ::: "memory"); }
    CVTW(rOd, 1);
    BARX();
    { unsigned short* tmp = A0; A0 = A1; A1 = A2; A2 = tmp; }
    if (t + 3 < NT) { STAGE(A2, (t + 3) * 32); LOADB(rOd, (t + 3) * 32); }
    STEP(A0, 1);
    if (t + 3 < NT) { asm volatile("s_waitcnt vmcnt(3)" ::: "memory"); }
    else            { asm volatile("s_waitcnt vmcnt(0)" ::: "memory"); }
    if (t + 2 < NT) CVTW(rEv, 0);
    BARX();
    { unsigned short* tmp = A0; A0 = A1; A1 = A2; A2 = tmp; }
  }

#pragma unroll
  for (int mi = 0; mi < 4; ++mi)
#pragma unroll
    for (int j = 0; j < 4; ++j) {
      int row = m_base + wm * 64 + mi * 16 + (lane >> 4) * 4 + j;
      if (row < count) {
        int tokv = tokl[e * T_ + row];
        float g = gatel[e * T_ + row];
#pragma unroll
        for (int ni = 0; ni < 2; ++ni)
          atomicAdd(&out[(size_t)tokv * H_ + n0 + wn * 32 + ni * 16 + (lane & 15)],
                    g * acc[mi][ni][j]);
      }
    }
}

extern "C" void kernel_launch(void* const* d_in, const int* in_sizes, int n_in,
                              void* d_out, int out_size, void* d_ws, size_t ws_size,
                              hipStream_t stream) {
  const float* x  = (const float*)d_in[0];
  const float* gw = (const float*)d_in[1];
  const float* w1 = (const float*)d_in[2];
  const float* w3 = (const float*)d_in[3];
  const float* w2 = (const float*)d_in[4];
  float* out = (float*)d_out;
  char* ws = (char*)d_ws;

  int* cnt = (int*)ws;
  int* base = (int*)(ws + 64);
  int* chunk = (int*)(ws + WS_CHUNK);
  int* tokl = (int*)(ws + WS_TOK);
  float* gatel = (float*)(ws + WS_GATE);
  unsigned short* xb = (unsigned short*)(ws + WS_XB);
  unsigned short* actb = (unsigned short*)(ws + WS_ACT);

  (void)hipMemsetAsync(d_out, 0, (size_t)T_ * H_ * sizeof(float), stream);
  (void)hipMemsetAsync(ws, 0, 64, stream);

  router_kernel<<<T_ / 4, 256, 0, stream>>>(x, gw, cnt, tokl, gatel, xb);
  prefix_kernel<<<1, 64, 0, stream>>>(cnt, base, chunk);
  ffn1_kernel<<<dim3(I_ / 64, MAXCH), 512, 0, stream>>>(xb, w1, w3, cnt, base, chunk, tokl, actb);
  ffn2_kernel<<<dim3(H_ / 64, MAXCH), 512, 0, stream>>>(actb, w2, cnt, base, chunk, tokl, gatel, out);
}

// Round 7
// 339.586 us; speedup vs baseline: 1.2702x; 1.2702x over previous
//
#include <hip/hip_runtime.h>

#define T_ 1024
#define H_ 2048
#define I_ 3200
#define E_ 8

typedef float fvec4 __attribute__((ext_vector_type(4)));
typedef float f32x4 __attribute__((ext_vector_type(4)));
typedef __bf16 bf16x8 __attribute__((ext_vector_type(8)));
typedef unsigned short u16x4 __attribute__((ext_vector_type(4)));

typedef const __attribute__((address_space(1))) void* gp1_t;
typedef __attribute__((address_space(3))) void* sp3_t;

// ---- ws layout (bytes) ----
#define WS_CHUNK 128
#define WS_TOK   512
#define WS_GATE  33280
#define WS_XB    66560
#define WS_ACT   4261888   // 3328 rows x 3200 bf16 (slack rows OOB-safe)
#define MAXCH    16

#define BARX() { asm volatile("s_waitcnt lgkmcnt(0)" ::: "memory"); \
    __builtin_amdgcn_sched_barrier(0); __builtin_amdgcn_s_barrier(); \
    __builtin_amdgcn_sched_barrier(0); }
#define BAR1() { __builtin_amdgcn_sched_barrier(0); __builtin_amdgcn_s_barrier(); \
    __builtin_amdgcn_sched_barrier(0); }

// ---------------- router + sparsemixer + list build + x->bf16 ----------------
__global__ __launch_bounds__(256) void router_kernel(const float* __restrict__ x,
                                                     const float* __restrict__ gw,
                                                     int* __restrict__ cnt,
                                                     int* __restrict__ tok,
                                                     float* __restrict__ gate,
                                                     unsigned short* __restrict__ xb) {
  const int lane = threadIdx.x & 63;
  const int wv = threadIdx.x >> 6;
  const int t = blockIdx.x * 4 + wv;

  const float* xp = x + (size_t)t * H_;
  fvec4 xr[8];
#pragma unroll
  for (int j = 0; j < 8; ++j) xr[j] = *(const fvec4*)(xp + j * 256 + lane * 4);

  unsigned short* xbp = xb + (size_t)t * H_;
#pragma unroll
  for (int j = 0; j < 8; ++j) {
    u16x4 o;
#pragma unroll
    for (int c = 0; c < 4; ++c) o[c] = __builtin_bit_cast(unsigned short, (__bf16)xr[j][c]);
    *(u16x4*)(xbp + j * 256 + lane * 4) = o;
  }

  float s[E_];
#pragma unroll
  for (int e = 0; e < E_; ++e) {
    const float* gp = gw + (size_t)e * H_;
    float p = 0.f;
#pragma unroll
    for (int j = 0; j < 8; ++j) {
      fvec4 g = *(const fvec4*)(gp + j * 256 + lane * 4);
      p = fmaf(xr[j][0], g[0], p); p = fmaf(xr[j][1], g[1], p);
      p = fmaf(xr[j][2], g[2], p); p = fmaf(xr[j][3], g[3], p);
    }
#pragma unroll
    for (int off = 32; off > 0; off >>= 1) p += __shfl_xor(p, off);
    s[e] = p;
  }

  float max1 = s[0]; int i1 = 0;
#pragma unroll
  for (int e = 1; e < E_; ++e) if (s[e] > max1) { max1 = s[e]; i1 = e; }
  float den1 = 0.f;
#pragma unroll
  for (int e = 0; e < E_; ++e) {
    float factor = fmaxf(fabsf(s[e]), max1);
    if ((max1 - s[e]) <= 0.02f * factor) den1 += expf(s[e] - max1);
  }
  float mult1 = 1.f / den1;

  float max2 = -INFINITY; int i2 = 0;
#pragma unroll
  for (int e = 0; e < E_; ++e) if (e != i1 && s[e] > max2) { max2 = s[e]; i2 = e; }
  float den2 = 0.f;
#pragma unroll
  for (int e = 0; e < E_; ++e) {
    if (e == i1) continue;
    float factor = fmaxf(fabsf(s[e]), max2);
    if ((max2 - s[e]) <= 0.02f * factor) den2 += expf(s[e] - max2);
  }
  float mult2 = 1.f / den2;

  if (lane == 0) {
    int p1 = atomicAdd(&cnt[i1], 1); tok[i1 * T_ + p1] = t; gate[i1 * T_ + p1] = mult1;
    int p2 = atomicAdd(&cnt[i2], 1); tok[i2 * T_ + p2] = t; gate[i2 * T_ + p2] = mult2;
  }
}

// ---------------- prefix (128-pad) + chunk table (256-row chunks) ----------------
__global__ void prefix_kernel(const int* __restrict__ cnt, int* __restrict__ base,
                              int* __restrict__ chunk) {
  if (threadIdx.x == 0 && blockIdx.x == 0) {
    int a = 0, c = 0;
    for (int e = 0; e < E_; ++e) {
      base[e] = a;
      int pc = (cnt[e] + 127) & ~127;
      for (int m = 0; m < pc; m += 256) { chunk[1 + c] = e; chunk[1 + MAXCH + c] = m; ++c; }
      a += pc;
    }
    base[E_] = a;
    chunk[0] = c;
  }
}

// ---- FFN1: BM=256, BN=32, BK=64, 8 waves, A 2-buf glds, B 2-deep reg->LDS ----
__global__ __launch_bounds__(512, 4) void ffn1_kernel(
    const unsigned short* __restrict__ xb, const float* __restrict__ w1,
    const float* __restrict__ w3, const int* __restrict__ cnt,
    const int* __restrict__ base, const int* __restrict__ chunk,
    const int* __restrict__ tokl, unsigned short* __restrict__ actb) {
  if ((int)blockIdx.y >= chunk[0]) return;
  const int e = chunk[1 + blockIdx.y];
  const int m_base = chunk[1 + MAXCH + blockIdx.y];
  const int ab = base[e];
  const int count = cnt[e];
  const int n0 = blockIdx.x * 32;
  const int tid = threadIdx.x;
  const int lane = tid & 63, wv = tid >> 6;   // 8 waves
  const int wm = wv >> 1, wn = wv & 1;        // per-wave 64x16 out

  __shared__ unsigned short Ab0[256 * 64];    // 32 KiB
  __shared__ unsigned short Ab1[256 * 64];    // 32 KiB
  __shared__ unsigned short B1s[2][32 * 64];  // 8 KiB
  __shared__ unsigned short B3s[2][32 * 64];  // 8 KiB   -> 80 KiB total

  // A gather sources (coalesced glds, pre-swizzled column)
  const unsigned short* aSrc[4];
  const int colg = ((lane & 7) ^ ((lane >> 3) & 7)) * 8;
#pragma unroll
  for (int i = 0; i < 4; ++i) {
    int r = m_base + wv * 32 + i * 8 + (lane >> 3);
    if (r >= count) r = count - 1;
    aSrc[i] = xb + (size_t)tokl[e * T_ + r] * H_ + colg;
  }
  // B tile: 32 rows (I) x 64 cols (K) f32; 16 thr/row, 4 f32 each
  const int brow = tid >> 4, w = tid & 15;
  const float* b1p = w1 + ((size_t)e * I_ + n0 + brow) * H_ + w * 4;
  const float* b3p = w3 + ((size_t)e * I_ + n0 + brow) * H_ + w * 4;
  const int wbyte = brow * 128 + ((((w >> 1)) ^ (brow & 7)) << 4) + (w & 1) * 8;

  f32x4 acc1[4], acc3[4];
#pragma unroll
  for (int mi = 0; mi < 4; ++mi) { acc1[mi] = (f32x4){0,0,0,0}; acc3[mi] = (f32x4){0,0,0,0}; }

  auto STAGE_A = [&](unsigned short* dst, int kb) {
#pragma unroll
    for (int i = 0; i < 4; ++i)
      __builtin_amdgcn_global_load_lds((gp1_t)(aSrc[i] + kb),
                                       (sp3_t)(dst + (wv * 32 + i * 8) * 64), 16, 0, 0);
  };
  auto LOADB = [&](fvec4& r1, fvec4& r3, int kb) {
    r1 = *(const fvec4*)(b1p + kb);
    r3 = *(const fvec4*)(b3p + kb);
  };
  auto CVTW = [&](fvec4& r1, fvec4& r3, int buf) {
    u16x4 v, u;
#pragma unroll
    for (int c = 0; c < 4; ++c) {
      v[c] = __builtin_bit_cast(unsigned short, (__bf16)r1[c]);
      u[c] = __builtin_bit_cast(unsigned short, (__bf16)r3[c]);
    }
    *(u16x4*)((char*)B1s[buf] + wbyte) = v;
    *(u16x4*)((char*)B3s[buf] + wbyte) = u;
  };
  auto STEP = [&](const unsigned short* A_, int bbuf) {
#pragma unroll
    for (int kk = 0; kk < 2; ++kk) {
      const int c16 = kk * 4 + (lane >> 4);
      bf16x8 af[4];
#pragma unroll
      for (int mi = 0; mi < 4; ++mi) {
        int ar = wm * 64 + mi * 16 + (lane & 15);
        af[mi] = *(const bf16x8*)((const char*)A_ + ar * 128 + ((c16 ^ (ar & 7)) << 4));
      }
      int br = wn * 16 + (lane & 15);
      bf16x8 f1 = *(const bf16x8*)((const char*)B1s[bbuf] + br * 128 + ((c16 ^ (br & 7)) << 4));
      bf16x8 f3 = *(const bf16x8*)((const char*)B3s[bbuf] + br * 128 + ((c16 ^ (br & 7)) << 4));
      __builtin_amdgcn_s_setprio(1);
#pragma unroll
      for (int mi = 0; mi < 4; ++mi) {
        acc1[mi] = __builtin_amdgcn_mfma_f32_16x16x32_bf16(af[mi], f1, acc1[mi], 0, 0, 0);
        acc3[mi] = __builtin_amdgcn_mfma_f32_16x16x32_bf16(af[mi], f3, acc3[mi], 0, 0, 0);
      }
      __builtin_amdgcn_s_setprio(0);
    }
  };

  const int NT = H_ / 64;  // 32 (even)
  fvec4 ra1, ra3, rb1, rb3;

  // prologue: A0,B0,A1,B1 in flight; drain A0,B0; cvt B0; issue B2
  STAGE_A(Ab0, 0);  LOADB(ra1, ra3, 0);
  STAGE_A(Ab1, 64); LOADB(rb1, rb3, 64);
  asm volatile("s_waitcnt vmcnt(6)" ::: "memory");
  CVTW(ra1, ra3, 0);
  LOADB(ra1, ra3, 128);
  BARX();

  for (int t = 0; t < NT; t += 2) {
    // ---- even tile t: A in Ab0, B in buf0 ----
    STEP(Ab0, 0);
    BAR1();                                    // all waves done reading Ab0
    if (t + 2 < NT) {
      STAGE_A(Ab0, (t + 2) * 64);
      asm volatile("s_waitcnt vmcnt(6)" ::: "memory");   // drains B(t+1), A(t+1)
    } else {
      asm volatile("s_waitcnt vmcnt(0)" ::: "memory");
    }
    CVTW(rb1, rb3, 1);                         // B(t+1) -> buf1
    if (t + 3 < NT) LOADB(rb1, rb3, (t + 3) * 64);
    BARX();
    // ---- odd tile t+1: A in Ab1, B in buf1 ----
    STEP(Ab1, 1);
    if (t + 2 >= NT) break;
    BAR1();
    if (t + 3 < NT) {
      STAGE_A(Ab1, (t + 3) * 64);
      asm volatile("s_waitcnt vmcnt(6)" ::: "memory");   // drains B(t+2), A(t+2)
    } else {
      asm volatile("s_waitcnt vmcnt(0)" ::: "memory");
    }
    CVTW(ra1, ra3, 0);                         // B(t+2) -> buf0
    if (t + 4 < NT) LOADB(ra1, ra3, (t + 4) * 64);
    BARX();
  }

  const int row_lim = (base[e + 1] - ab) - m_base;
#pragma unroll
  for (int mi = 0; mi < 4; ++mi)
#pragma unroll
    for (int j = 0; j < 4; ++j) {
      int row = wm * 64 + mi * 16 + (lane >> 4) * 4 + j;
      if (row < row_lim) {
        float h1 = acc1[mi][j];
        float a = (h1 / (1.f + __expf(-h1))) * acc3[mi][j];
        actb[(size_t)(ab + m_base + row) * I_ + n0 + wn * 16 + (lane & 15)] =
            __builtin_bit_cast(unsigned short, (__bf16)a);
      }
    }
}

// ---- FFN2: BM=256, BN=32, BK=64, same pipeline, single B ----
__global__ __launch_bounds__(512, 4) void ffn2_kernel(
    const unsigned short* __restrict__ actb, const float* __restrict__ w2,
    const int* __restrict__ cnt, const int* __restrict__ base,
    const int* __restrict__ chunk, const int* __restrict__ tokl,
    const float* __restrict__ gatel, float* __restrict__ out) {
  if ((int)blockIdx.y >= chunk[0]) return;
  const int e = chunk[1 + blockIdx.y];
  const int m_base = chunk[1 + MAXCH + blockIdx.y];
  const int count = cnt[e];
  if (m_base >= count) return;
  const int ab = base[e];
  const int n0 = blockIdx.x * 32;
  const int tid = threadIdx.x;
  const int lane = tid & 63, wv = tid >> 6;
  const int wm = wv >> 1, wn = wv & 1;

  __shared__ unsigned short Ab0[256 * 64];    // 32 KiB
  __shared__ unsigned short Ab1[256 * 64];    // 32 KiB
  __shared__ unsigned short Bs[2][32 * 64];   // 8 KiB  -> 72 KiB

  const unsigned short* aSrc[4];
  const int colg = ((lane & 7) ^ ((lane >> 3) & 7)) * 8;
#pragma unroll
  for (int i = 0; i < 4; ++i) {
    int r = ab + m_base + wv * 32 + i * 8 + (lane >> 3);
    aSrc[i] = actb + (size_t)r * I_ + colg;
  }
  const int brow = tid >> 4, w = tid & 15;
  const float* bp = w2 + ((size_t)e * H_ + n0 + brow) * I_ + w * 4;
  const int wbyte = brow * 128 + ((((w >> 1)) ^ (brow & 7)) << 4) + (w & 1) * 8;

  f32x4 acc[4];
#pragma unroll
  for (int mi = 0; mi < 4; ++mi) acc[mi] = (f32x4){0,0,0,0};

  auto STAGE_A = [&](unsigned short* dst, int kb) {
#pragma unroll
    for (int i = 0; i < 4; ++i)
      __builtin_amdgcn_global_load_lds((gp1_t)(aSrc[i] + kb),
                                       (sp3_t)(dst + (wv * 32 + i * 8) * 64), 16, 0, 0);
  };
  auto LOADB = [&](fvec4& r, int kb) { r = *(const fvec4*)(bp + kb); };
  auto CVTW = [&](fvec4& r, int buf) {
    u16x4 v;
#pragma unroll
    for (int c = 0; c < 4; ++c) v[c] = __builtin_bit_cast(unsigned short, (__bf16)r[c]);
    *(u16x4*)((char*)Bs[buf] + wbyte) = v;
  };
  auto STEP = [&](const unsigned short* A_, int bbuf) {
#pragma unroll
    for (int kk = 0; kk < 2; ++kk) {
      const int c16 = kk * 4 + (lane >> 4);
      bf16x8 af[4];
#pragma unroll
      for (int mi = 0; mi < 4; ++mi) {
        int ar = wm * 64 + mi * 16 + (lane & 15);
        af[mi] = *(const bf16x8*)((const char*)A_ + ar * 128 + ((c16 ^ (ar & 7)) << 4));
      }
      int br = wn * 16 + (lane & 15);
      bf16x8 f = *(const bf16x8*)((const char*)Bs[bbuf] + br * 128 + ((c16 ^ (br & 7)) << 4));
      __builtin_amdgcn_s_setprio(1);
#pragma unroll
      for (int mi = 0; mi < 4; ++mi)
        acc[mi] = __builtin_amdgcn_mfma_f32_16x16x32_bf16(af[mi], f, acc[mi], 0, 0, 0);
      __builtin_amdgcn_s_setprio(0);
    }
  };

  const int NT = I_ / 64;  // 50 (even)
  fvec4 ra, rb;

  STAGE_A(Ab0, 0);  LOADB(ra, 0);
  STAGE_A(Ab1, 64); LOADB(rb, 64);
  asm volatile("s_waitcnt vmcnt(5)" ::: "memory");
  CVTW(ra, 0);
  LOADB(ra, 128);
  BARX();

  for (int t = 0; t < NT; t += 2) {
    STEP(Ab0, 0);
    BAR1();
    if (t + 2 < NT) {
      STAGE_A(Ab0, (t + 2) * 64);
      asm volatile("s_waitcnt vmcnt(5)" ::: "memory");
    } else {
      asm volatile("s_waitcnt vmcnt(0)" ::: "memory");
    }
    CVTW(rb, 1);
    if (t + 3 < NT) LOADB(rb, (t + 3) * 64);
    BARX();
    STEP(Ab1, 1);
    if (t + 2 >= NT) break;
    BAR1();
    if (t + 3 < NT) {
      STAGE_A(Ab1, (t + 3) * 64);
      asm volatile("s_waitcnt vmcnt(5)" ::: "memory");
    } else {
      asm volatile("s_waitcnt vmcnt(0)" ::: "memory");
    }
    CVTW(ra, 0);
    if (t + 4 < NT) LOADB(ra, (t + 4) * 64);
    BARX();
  }

#pragma unroll
  for (int mi = 0; mi < 4; ++mi)
#pragma unroll
    for (int j = 0; j < 4; ++j) {
      int row = m_base + wm * 64 + mi * 16 + (lane >> 4) * 4 + j;
      if (row < count) {
        int tokv = tokl[e * T_ + row];
        float g = gatel[e * T_ + row];
        atomicAdd(&out[(size_t)tokv * H_ + n0 + wn * 16 + (lane & 15)], g * acc[mi][j]);
      }
    }
}

extern "C" void kernel_launch(void* const* d_in, const int* in_sizes, int n_in,
                              void* d_out, int out_size, void* d_ws, size_t ws_size,
                              hipStream_t stream) {
  const float* x  = (const float*)d_in[0];
  const float* gw = (const float*)d_in[1];
  const float* w1 = (const float*)d_in[2];
  const float* w3 = (const float*)d_in[3];
  const float* w2 = (const float*)d_in[4];
  float* out = (float*)d_out;
  char* ws = (char*)d_ws;

  int* cnt = (int*)ws;
  int* base = (int*)(ws + 64);
  int* chunk = (int*)(ws + WS_CHUNK);
  int* tokl = (int*)(ws + WS_TOK);
  float* gatel = (float*)(ws + WS_GATE);
  unsigned short* xb = (unsigned short*)(ws + WS_XB);
  unsigned short* actb = (unsigned short*)(ws + WS_ACT);

  (void)hipMemsetAsync(d_out, 0, (size_t)T_ * H_ * sizeof(float), stream);
  (void)hipMemsetAsync(ws, 0, 64, stream);

  router_kernel<<<T_ / 4, 256, 0, stream>>>(x, gw, cnt, tokl, gatel, xb);
  prefix_kernel<<<1, 64, 0, stream>>>(cnt, base, chunk);
  ffn1_kernel<<<dim3(I_ / 32, MAXCH), 512, 0, stream>>>(xb, w1, w3, cnt, base, chunk, tokl, actb);
  ffn2_kernel<<<dim3(H_ / 32, MAXCH), 512, 0, stream>>>(actb, w2, cnt, base, chunk, tokl, gatel, out);
}